// Round 2
// 1005.837 us; speedup vs baseline: 1.0112x; 1.0112x over previous
//
#include <hip/hip_runtime.h>
#include <hip/hip_bf16.h>
#include <cstdint>
#include <cstddef>

#define M_ROWS 65536
#define K_DIM  1024
#define N_OUT  2048
#define NTILE  16   // K_DIM / 64 K-tiles

typedef __attribute__((ext_vector_type(8))) short short8;
typedef __attribute__((ext_vector_type(4))) float floatx4;

__device__ __forceinline__ unsigned short f2bf(float f) {
  unsigned int u = __float_as_uint(f);
  u += 0x7fffu + ((u >> 16) & 1u);
  return (unsigned short)(u >> 16);
}

// ---------------- Kernel 1: LayerNorm fp32 -> bf16, one wave per row --------
__global__ __launch_bounds__(256) void ln_bf16_kernel(
    const float* __restrict__ x, const float* __restrict__ gamma,
    const float* __restrict__ beta, ushort* __restrict__ xn) {
  const int wave = threadIdx.x >> 6;
  const int lane = threadIdx.x & 63;
  const size_t row = (size_t)blockIdx.x * 4 + wave;
  const float4* xr = (const float4*)(x + row * K_DIM);
  float4 v[4];
  float s = 0.f, ss = 0.f;
#pragma unroll
  for (int i = 0; i < 4; ++i) {
    v[i] = xr[lane + 64 * i];
    s  += v[i].x + v[i].y + v[i].z + v[i].w;
    ss += v[i].x * v[i].x + v[i].y * v[i].y + v[i].z * v[i].z + v[i].w * v[i].w;
  }
#pragma unroll
  for (int off = 32; off; off >>= 1) {
    s  += __shfl_xor(s, off, 64);
    ss += __shfl_xor(ss, off, 64);
  }
  const float mu = s * (1.0f / 1024.0f);
  const float rstd = rsqrtf(ss * (1.0f / 1024.0f) - mu * mu + 1e-5f);
  ushort4* orow = (ushort4*)(xn + row * K_DIM);
#pragma unroll
  for (int i = 0; i < 4; ++i) {
    const float4 g  = ((const float4*)gamma)[lane + 64 * i];
    const float4 bb = ((const float4*)beta)[lane + 64 * i];
    ushort4 o;
    o.x = f2bf((v[i].x - mu) * rstd * g.x + bb.x);
    o.y = f2bf((v[i].y - mu) * rstd * g.y + bb.y);
    o.z = f2bf((v[i].z - mu) * rstd * g.z + bb.z);
    o.w = f2bf((v[i].w - mu) * rstd * g.w + bb.w);
    orow[lane + 64 * i] = o;
  }
}

// ---------------- Kernel 2: W fp32 -> bf16 ----------------------------------
__global__ __launch_bounds__(256) void wconv_kernel(const float* __restrict__ W,
                                                    ushort* __restrict__ Wb) {
  const int i = blockIdx.x * 256 + threadIdx.x;  // one float4 per thread
  const float4 w = ((const float4*)W)[i];
  ushort4 o;
  o.x = f2bf(w.x); o.y = f2bf(w.y); o.z = f2bf(w.z); o.w = f2bf(w.w);
  ((ushort4*)Wb)[i] = o;
}

// ---------------- Kernel 3: 256x256 8-phase bf16 MFMA GEMM ------------------
// T1 XCD swizzle + T2 st-swizzle (linear gload_lds dest, pre-swizzled global
// source, XOR'd ds_read) + T3/T4 8-phase counted-vmcnt + T5 setprio.
// 512 threads = 8 waves (2M x 4N), per-wave 128x64 output, BK=64, 16 K-tiles.
// LDS: 2 x (A 32KB + B 32KB) = 128 KiB double buffer, 1 block/CU.
__device__ __forceinline__ void async_copy16(const ushort* g, ushort* l) {
  __builtin_amdgcn_global_load_lds(
      (const __attribute__((address_space(1))) void*)g,
      (__attribute__((address_space(3))) void*)l, 16, 0, 0);
}

__global__ __launch_bounds__(512, 2) void gemm_kernel(
    const ushort* __restrict__ A,   // M x K bf16 (xn)
    const ushort* __restrict__ Bw,  // N_OUT x K bf16 (W)
    const float* __restrict__ bias, float* __restrict__ out) {
  __shared__ ushort As[2][256 * 64];  // 64 KiB
  __shared__ ushort Bs[2][256 * 64];  // 64 KiB

  const int tid = threadIdx.x;
  // T1: bijective XCD swizzle (2048 blocks % 8 XCDs == 0). Each XCD gets 256
  // consecutive wgids; bn fastest so same-A-panel blocks share one L2.
  const int bid = blockIdx.x;
  const int wg  = (bid & 7) * 256 + (bid >> 3);
  const int bn  = wg & 7;    // 8 N-tiles of 256
  const int bm  = wg >> 3;   // 256 M-tiles of 256

  const int lane = tid & 63;
  const int wv   = tid >> 6;
  const int wm   = wv & 1;   // wave row (2)
  const int wn   = wv >> 1;  // wave col (4)
  const int quad = lane >> 4;
  const int l16  = lane & 15;
  const int swz  = (l16 & 7) << 4;  // T2 read-side XOR (byte bits 4-6)

  // Staging: per-instruction 512 threads x 16B = 64 rows x 128B, LINEAR dest.
  // Source column is inverse-swizzled so LDS[linear ^ swz(row)] holds the
  // element ds_read expects (same involution both sides; rule #21).
  const int srow = tid >> 3;                        // 0..63
  const int scol = ((tid & 7) ^ (srow & 7)) * 8;    // element offset in K-window
  const ushort* Ag = A  + (size_t)(bm * 256 + srow) * K_DIM + scol;
  const ushort* Bg = Bw + (size_t)(bn * 256 + srow) * K_DIM + scol;
  ushort* Ad = &As[0][0] + srow * 64 + (tid & 7) * 8;  // +tid*16B contiguous
  ushort* Bd = &Bs[0][0] + srow * 64 + (tid & 7) * 8;

#define STAGE_A(buf, h, kt) do {                                         \
    const ushort* g_ = Ag + (size_t)((h) * 128) * K_DIM + (kt) * 64;     \
    ushort* l_ = Ad + (buf) * 16384 + (h) * 8192;                        \
    async_copy16(g_, l_);                                                \
    async_copy16(g_ + (size_t)64 * K_DIM, l_ + 4096);                    \
  } while (0)
#define STAGE_B(buf, h, kt) do {                                         \
    const ushort* g_ = Bg + (size_t)((h) * 128) * K_DIM + (kt) * 64;     \
    ushort* l_ = Bd + (buf) * 16384 + (h) * 8192;                        \
    async_copy16(g_, l_);                                                \
    async_copy16(g_ + (size_t)64 * K_DIM, l_ + 4096);                    \
  } while (0)

  // Prologue: K-tile 0 (A+B) + B-halves of K-tile 1. vmcnt(4) lands the 8
  // oldest loads (= all of K-tile 0); B(1)'s 4 loads stay in flight.
  STAGE_A(0, 0, 0); STAGE_A(0, 1, 0);
  STAGE_B(0, 0, 0); STAGE_B(0, 1, 0);
  STAGE_B(1, 0, 1); STAGE_B(1, 1, 1);
  asm volatile("s_waitcnt vmcnt(4)" ::: "memory");
  __builtin_amdgcn_s_barrier();
  asm volatile("" ::: "memory");

  floatx4 acc[8][4] = {};
  const char* AsB = (const char*)&As[0][0];
  const char* BsB = (const char*)&Bs[0][0];

  // K-loop: 4 phases per K-tile. Phase q: ds_read A-quadrant q (+ all B frags
  // at q0, held in regs for the K-tile); issue one half-tile stage
  // (q0/q1 -> A(t+1) into buf^1, freed last phase of t-1; q2/q3 -> B(t+2)
  // into current buf, whose B region was consumed at q0); barrier;
  // lgkmcnt(0); 16 MFMA under setprio(1); boundary vmcnt(4) at q3 (the 4
  // newest loads = B(t+2) legitimately cross the barrier); barrier.
#pragma unroll 1
  for (int t = 0; t < NTILE; ++t) {
    const char* Ab = AsB + (t & 1) * 32768;
    const char* Bb = BsB + (t & 1) * 32768;
    short8 bfr[4][2];
#pragma unroll
    for (int q = 0; q < 4; ++q) {
      short8 afr[2][2];
      if (q == 0) {
#pragma unroll
        for (int ni = 0; ni < 4; ++ni)
#pragma unroll
          for (int ks = 0; ks < 2; ++ks)
            bfr[ni][ks] = *(const short8*)(
                Bb + (wn * 64 + ni * 16 + l16) * 128 +
                ((ks * 64 + quad * 16) ^ swz));
      }
#pragma unroll
      for (int j = 0; j < 2; ++j)
#pragma unroll
        for (int ks = 0; ks < 2; ++ks)
          afr[j][ks] = *(const short8*)(
              Ab + (wm * 128 + (q * 2 + j) * 16 + l16) * 128 +
              ((ks * 64 + quad * 16) ^ swz));

      if (q == 0)      { if (t + 1 < NTILE) STAGE_A((t + 1) & 1, 0, t + 1); }
      else if (q == 1) { if (t + 1 < NTILE) STAGE_A((t + 1) & 1, 1, t + 1); }
      else if (q == 2) { if (t + 2 < NTILE) STAGE_B(t & 1, 0, t + 2); }
      else             { if (t + 2 < NTILE) STAGE_B(t & 1, 1, t + 2); }

      __builtin_amdgcn_s_barrier();
      asm volatile("s_waitcnt lgkmcnt(0)" ::: "memory");
      __builtin_amdgcn_sched_barrier(0);
      __builtin_amdgcn_s_setprio(1);
#pragma unroll
      for (int j = 0; j < 2; ++j)
#pragma unroll
        for (int ni = 0; ni < 4; ++ni)
#pragma unroll
          for (int ks = 0; ks < 2; ++ks)
            acc[q * 2 + j][ni] = __builtin_amdgcn_mfma_f32_16x16x32_bf16(
                afr[j][ks], bfr[ni][ks], acc[q * 2 + j][ni], 0, 0, 0);
      __builtin_amdgcn_s_setprio(0);

      if (q == 3) {
        if (t == NTILE - 2)     asm volatile("s_waitcnt vmcnt(0)" ::: "memory");
        else if (t < NTILE - 2) asm volatile("s_waitcnt vmcnt(4)" ::: "memory");
      }
      __builtin_amdgcn_s_barrier();
      asm volatile("" ::: "memory");
    }
  }
#undef STAGE_A
#undef STAGE_B

  // Epilogue: bias + patch-split scatter.
  // D layout (16x16x32): row = quad*4 + r, col = l16.
  const int obase = bn * 256 + wn * 64;
  float bv[4];
#pragma unroll
  for (int ni = 0; ni < 4; ++ni) bv[ni] = bias[obase + ni * 16 + l16];

#pragma unroll
  for (int mi = 0; mi < 8; ++mi) {
    const int m0 = bm * 256 + wm * 128 + mi * 16 + quad * 4;
#pragma unroll
    for (int r = 0; r < 4; ++r) {
      const int m = m0 + r;
      const int bnn = m >> 10;
      const int h = (m >> 5) & 31;
      const int w = m & 31;
      const size_t rowbase = (((size_t)(bnn * 64 + 2 * h)) * 64 + 2 * w) * 512;
#pragma unroll
      for (int ni = 0; ni < 4; ++ni) {
        const int o = obase + ni * 16 + l16;
        const int p1 = (o >> 10) & 1;
        const int p2 = (o >> 9) & 1;
        const int f = o & 511;
        out[rowbase + (size_t)p1 * 32768 + (size_t)p2 * 512 + f] =
            acc[mi][ni][r] + bv[ni];
      }
    }
  }
}

// ---------------- Fallback (only if workspace too small): fused fp32 --------
__global__ __launch_bounds__(256) void fused_fallback(
    const float* __restrict__ x, const float* __restrict__ gamma,
    const float* __restrict__ beta, const float* __restrict__ W,
    const float* __restrict__ b, float* __restrict__ out) {
  __shared__ float xs[1024];
  __shared__ float red[8];
  const int m = blockIdx.x;
  const int t = threadIdx.x;
  const float4 v = ((const float4*)(x + (size_t)m * 1024))[t];
  float s = v.x + v.y + v.z + v.w;
  float ss = v.x * v.x + v.y * v.y + v.z * v.z + v.w * v.w;
#pragma unroll
  for (int off = 32; off; off >>= 1) {
    s  += __shfl_xor(s, off, 64);
    ss += __shfl_xor(ss, off, 64);
  }
  if ((t & 63) == 0) { red[t >> 6] = s; red[4 + (t >> 6)] = ss; }
  __syncthreads();
  const float S = red[0] + red[1] + red[2] + red[3];
  const float SS = red[4] + red[5] + red[6] + red[7];
  const float mu = S * (1.0f / 1024.0f);
  const float rstd = rsqrtf(SS * (1.0f / 1024.0f) - mu * mu + 1e-5f);
  const float4 g = ((const float4*)gamma)[t];
  const float4 be = ((const float4*)beta)[t];
  float4 xn;
  xn.x = (v.x - mu) * rstd * g.x + be.x;
  xn.y = (v.y - mu) * rstd * g.y + be.y;
  xn.z = (v.z - mu) * rstd * g.z + be.z;
  xn.w = (v.w - mu) * rstd * g.w + be.w;
  ((float4*)xs)[t] = xn;
  __syncthreads();
  const int bnn = m >> 10, h = (m >> 5) & 31, w = m & 31;
  const size_t rowbase = (((size_t)(bnn * 64 + 2 * h)) * 64 + 2 * w) * 512;
#pragma unroll 1
  for (int i = 0; i < 8; ++i) {
    const int o = t + i * 256;
    const float4* wr = (const float4*)(W + (size_t)o * 1024);
    float acc = 0.f;
    for (int k = 0; k < 256; ++k) {
      const float4 wv = wr[k];
      const float4 xv = ((const float4*)xs)[k];
      acc += wv.x * xv.x + wv.y * xv.y + wv.z * xv.z + wv.w * xv.w;
    }
    const int p1 = (o >> 10) & 1, p2 = (o >> 9) & 1, f = o & 511;
    out[rowbase + (size_t)p1 * 32768 + (size_t)p2 * 512 + f] = acc + b[o];
  }
}

extern "C" void kernel_launch(void* const* d_in, const int* in_sizes, int n_in,
                              void* d_out, int out_size, void* d_ws, size_t ws_size,
                              hipStream_t stream) {
  const float* x     = (const float*)d_in[0];
  const float* gamma = (const float*)d_in[1];
  const float* beta  = (const float*)d_in[2];
  const float* W     = (const float*)d_in[3];
  const float* b     = (const float*)d_in[4];
  float* out = (float*)d_out;

  const size_t xn_bytes = (size_t)M_ROWS * K_DIM * 2;       // 134 MB
  const size_t wb_bytes = (size_t)N_OUT * K_DIM * 2;        // 4 MB
  if (ws_size >= xn_bytes + wb_bytes) {
    ushort* xn = (ushort*)d_ws;
    ushort* Wb = (ushort*)((char*)d_ws + xn_bytes);
    ln_bf16_kernel<<<M_ROWS / 4, 256, 0, stream>>>(x, gamma, beta, xn);
    wconv_kernel<<<(N_OUT * K_DIM / 4) / 256, 256, 0, stream>>>(W, Wb);
    gemm_kernel<<<(M_ROWS / 256) * (N_OUT / 256), 512, 0, stream>>>(xn, Wb, b, out);
  } else {
    fused_fallback<<<M_ROWS, 256, 0, stream>>>(x, gamma, beta, W, b, out);
  }
}